// Round 2
// baseline (523.077 us; speedup 1.0000x reference)
//
#include <hip/hip_runtime.h>

// CompoundClassifier: per-edge 2-layer MLP with feature gather.
//   h = relu([x_ing[s], x_cmp[d]] @ W1 + b1); out = sigmoid(h @ W2 + b2)
// Round 2: LDS-free design. Each wave owns 16 edges x all 128 cols.
//   - W1 B-fragments (8 n-tiles x 8 k-steps) pinned in 128 VGPRs per wave
//   - A-fragments loaded DIRECTLY from global (gather is random; LDS staging
//     bought no coalescing and cost ~80us in LDS throughput + conflicts)
//   - layer 2 fused: relu -> dot W2 -> shfl_xor reduce over 16-lane m-group
//   - no __shared__, no __syncthreads: waves fully independent, TLP hides gather

#define H       128
#define NI      20000
#define NC      10000
#define NE      1000000
#define TPW     16                  // edges per wave-tile
#define NT      (NE / TPW)          // 62500 tiles (exact)
#define GRID    3125                // 12500 waves, 5 tiles/wave (exact)

typedef _Float16 half8  __attribute__((ext_vector_type(8)));
typedef _Float16 half4v __attribute__((ext_vector_type(4)));
typedef float    floatx4 __attribute__((ext_vector_type(4)));

// d_ws layout in _Float16 elements:
#define XIN_OFF  0
#define XCMP_OFF (NI * H)
#define W1T_OFF  (NI * H + NC * H)   // W1 transposed [n][k], contiguous k

#define FEAT_BLOCKS ((NI + NC) * H / 4 / 256)   // 3750

__global__ void cvt_all(const float* __restrict__ xin,
                        const float* __restrict__ xcmp,
                        const float* __restrict__ W1,
                        _Float16* __restrict__ ws) {
    int b = blockIdx.x;
    if (b < FEAT_BLOCKS) {
        long i = ((long)b * 256 + threadIdx.x) * 4;
        float4 v;
        if (i < (long)NI * H) v = *(const float4*)(xin + i);
        else                  v = *(const float4*)(xcmp + (i - (long)NI * H));
        half4v h = { (_Float16)v.x, (_Float16)v.y, (_Float16)v.z, (_Float16)v.w };
        *(half4v*)(ws + i) = h;
    } else {
        int i = (b - FEAT_BLOCKS) * 256 + threadIdx.x;   // over 128*256
        int n = i >> 8, k = i & 255;
        ws[W1T_OFF + i] = (_Float16)W1[k * H + n];       // W1 is [256][128] row-major
    }
}

__launch_bounds__(256, 2)
__global__ void edge_mlp(const _Float16* __restrict__ ws,
                         const int* __restrict__ src_idx,
                         const int* __restrict__ dst_idx,
                         const float* __restrict__ b1,
                         const float* __restrict__ W2,
                         const float* __restrict__ b2p,
                         float* __restrict__ out) {
    const int tid  = threadIdx.x;
    const int lane = tid & 63;
    const int w    = tid >> 6;      // wave 0..3
    const int quad = lane >> 4;     // 0..3 -> k-position within fragments
    const int m    = lane & 15;     // edge-within-tile (A row) / col-within-ntile (B col)

    const _Float16* xin_h  = ws + XIN_OFF;
    const _Float16* xcmp_h = ws + XCMP_OFF;
    const _Float16* w1t    = ws + W1T_OFF;

    // ---- per-wave setup: all of W1 as B-fragments (8 nt x 8 ks), 128 VGPRs
    half8 bf[8][8];
    float b1v[8], w2v[8];
#pragma unroll
    for (int nt = 0; nt < 8; ++nt) {
        int n = nt * 16 + m;
#pragma unroll
        for (int ks = 0; ks < 8; ++ks)
            bf[nt][ks] = *(const half8*)(w1t + n * 256 + ks * 32 + quad * 8);
        b1v[nt] = b1[n];
        w2v[nt] = W2[n];
    }
    const float b2v = b2p[0];

    const int wid    = blockIdx.x * 4 + w;   // global wave id, 0..12499
    const int stride = GRID * 4;

    // prefetch first tile's indices
    int sr = 0, dr = 0;
    if (wid < NT) {
        sr = src_idx[wid * TPW + m];
        dr = dst_idx[wid * TPW + m];
    }

    for (int tile = wid; tile < NT; tile += stride) {
        // ---- A-fragments straight from global: lane (quad,m) reads edge m's
        // row, 16B chunk at k = ks*32 + quad*8 (ks 0..3 src / 4..7 dst)
        const _Float16* sp = xin_h  + (long)sr * H + quad * 8;
        const _Float16* dp = xcmp_h + (long)dr * H + quad * 8;
        half8 af[8];
#pragma unroll
        for (int ks = 0; ks < 4; ++ks) af[ks]     = *(const half8*)(sp + ks * 32);
#pragma unroll
        for (int ks = 0; ks < 4; ++ks) af[ks + 4] = *(const half8*)(dp + ks * 32);

        // prefetch next tile's indices while MFMAs run
        int nxt = tile + stride;
        int sr2 = sr, dr2 = dr;
        if (nxt < NT) {
            sr2 = src_idx[nxt * TPW + m];
            dr2 = dst_idx[nxt * TPW + m];
        }

        // ---- 16 edges x 128 cols: 8 ks x 8 nt MFMAs, ks outer for indep chains
        floatx4 acc[8];
#pragma unroll
        for (int nt = 0; nt < 8; ++nt) acc[nt] = (floatx4)0.0f;
#pragma unroll
        for (int ks = 0; ks < 8; ++ks)
#pragma unroll
            for (int nt = 0; nt < 8; ++nt)
                acc[nt] = __builtin_amdgcn_mfma_f32_16x16x32_f16(
                    af[ks], bf[nt][ks], acc[nt], 0, 0, 0);

        // ---- fused layer 2: relu+b1, dot W2, reduce over the 16-lane m-group
        // C/D: col = nt*16 + m, row(edge) = quad*4 + r
        float p[4] = {0.f, 0.f, 0.f, 0.f};
#pragma unroll
        for (int nt = 0; nt < 8; ++nt)
#pragma unroll
            for (int r = 0; r < 4; ++r) {
                float v = fmaxf(acc[nt][r] + b1v[nt], 0.0f);
                p[r] = fmaf(v, w2v[nt], p[r]);
            }
#pragma unroll
        for (int off = 1; off < 16; off <<= 1)
#pragma unroll
            for (int r = 0; r < 4; ++r)
                p[r] += __shfl_xor(p[r], off);

        if (m == 0) {
            float4 f;
            f.x = 1.0f / (1.0f + expf(-(p[0] + b2v)));
            f.y = 1.0f / (1.0f + expf(-(p[1] + b2v)));
            f.z = 1.0f / (1.0f + expf(-(p[2] + b2v)));
            f.w = 1.0f / (1.0f + expf(-(p[3] + b2v)));
            *(float4*)(out + tile * TPW + quad * 4) = f;
        }

        sr = sr2; dr = dr2;
    }
}

extern "C" void kernel_launch(void* const* d_in, const int* in_sizes, int n_in,
                              void* d_out, int out_size, void* d_ws, size_t ws_size,
                              hipStream_t stream) {
    const float* xin  = (const float*)d_in[0];
    const float* xcmp = (const float*)d_in[1];
    const int*   eidx = (const int*)d_in[2];    // [2, E]: first E = src, next E = dst
    const float* W1   = (const float*)d_in[3];
    const float* b1   = (const float*)d_in[4];
    const float* W2   = (const float*)d_in[5];
    const float* b2   = (const float*)d_in[6];
    float* out = (float*)d_out;
    _Float16* ws = (_Float16*)d_ws;             // ~7.8 MB used

    hipLaunchKernelGGL(cvt_all, dim3(FEAT_BLOCKS + 128), dim3(256), 0, stream,
                       xin, xcmp, W1, ws);
    hipLaunchKernelGGL(edge_mlp, dim3(GRID), dim3(256), 0, stream,
                       ws, eidx, eidx + NE, b1, W2, b2, out);
}

// Round 3
// 127.601 us; speedup vs baseline: 4.0993x; 4.0993x over previous
//
#include <hip/hip_runtime.h>

// CompoundClassifier, round 3: eliminate the edge GEMM algebraically.
//   h = relu([src,dst]@W1 + b1) = relu(P[s] + Q[d]),
//     P = x_ing @ W1[:128]  (20000x128, precomputed, f16)
//     Q = x_cmp @ W1[128:] + b1 (10000x128, precomputed, f16)
//   out[e] = sigmoid(relu(P[s]+Q[d]) . W2 + b2)
// Edge compute drops 65.5 GFLOP -> 0.4 GFLOP; edge kernel is a cache-BW-bound
// gather (P,Q = 7.7 MB, L2/L3-resident; 512 MB of row reads).
// Round-2 lesson: W1-per-wave = 256 VGPRs -> spills; here only pq_gemm uses
// MFMA (proven 16x16x32 fragment layouts) and it's 1875 tiny blocks.

#define H  128
#define NI 20000
#define NC 10000
#define NE 1000000

typedef _Float16 half8  __attribute__((ext_vector_type(8)));
typedef float    floatx4 __attribute__((ext_vector_type(4)));

// d_ws layout in _Float16 elements (7.68 MB total)
#define P_OFF 0
#define Q_OFF (NI * H)

#define PB (NI / 16)   // 1250 P row-tiles
#define QB (NC / 16)   // 625  Q row-tiles

// ---- precompute P and Q with 16x16x32 f16 MFMA ----
// block = 4 waves; wave w covers cols [w*32, w*32+32); 16 rows per block.
// A-frag: lane(quad,m) holds X[row=m][k=quad*8+j]  (j=0..7)
// B-frag: lane(quad,m) holds W[k=quad*8+j][col=m]
// C/D:    col = lane&15, row = quad*4 + reg        (HW-verified layouts)
__launch_bounds__(256)
__global__ void pq_gemm(const float* __restrict__ xin,
                        const float* __restrict__ xcmp,
                        const float* __restrict__ W1,   // [256][128] row-major
                        const float* __restrict__ b1,
                        _Float16* __restrict__ ws) {
    const int b    = blockIdx.x;
    const bool isQ = (b >= PB);
    const int  rb  = (isQ ? b - PB : b) * 16;
    const float* X = isQ ? xcmp : xin;
    const int kofs = isQ ? H : 0;           // W1 row offset: src part vs dst part
    _Float16* OUT  = ws + (isQ ? Q_OFF : P_OFF);

    const int lane = threadIdx.x & 63;
    const int w    = threadIdx.x >> 6;
    const int quad = lane >> 4;
    const int m    = lane & 15;

    // B-fragments: cvt W1 f32 -> f16 on the fly (64 scalar loads, L1/L2-resident)
    half8 bf[2][4];
    float b1v[2];
#pragma unroll
    for (int nt = 0; nt < 2; ++nt) {
        const int n = w * 32 + nt * 16 + m;
#pragma unroll
        for (int ks = 0; ks < 4; ++ks) {
            const int k0 = kofs + ks * 32 + quad * 8;
#pragma unroll
            for (int j = 0; j < 8; ++j)
                bf[nt][ks][j] = (_Float16)W1[(k0 + j) * H + n];
        }
        b1v[nt] = isQ ? b1[n] : 0.0f;
    }

    // A-fragments: row rb+m, contiguous 8 floats -> half8
    half8 af[4];
    const float* xr = X + (long)(rb + m) * H + quad * 8;
#pragma unroll
    for (int ks = 0; ks < 4; ++ks) {
        float4 a = *(const float4*)(xr + ks * 32);
        float4 c = *(const float4*)(xr + ks * 32 + 4);
        half8 v = { (_Float16)a.x, (_Float16)a.y, (_Float16)a.z, (_Float16)a.w,
                    (_Float16)c.x, (_Float16)c.y, (_Float16)c.z, (_Float16)c.w };
        af[ks] = v;
    }

    floatx4 acc[2] = { (floatx4)0.0f, (floatx4)0.0f };
#pragma unroll
    for (int ks = 0; ks < 4; ++ks)
#pragma unroll
        for (int nt = 0; nt < 2; ++nt)
            acc[nt] = __builtin_amdgcn_mfma_f32_16x16x32_f16(af[ks], bf[nt][ks], acc[nt], 0, 0, 0);

#pragma unroll
    for (int nt = 0; nt < 2; ++nt) {
        const int col = w * 32 + nt * 16 + m;
#pragma unroll
        for (int r = 0; r < 4; ++r) {
            const int row = rb + quad * 4 + r;
            OUT[row * H + col] = (_Float16)(acc[nt][r] + b1v[nt]);
        }
    }
}

// ---- edge kernel: 8 threads per edge, each owns 16B of each 128B line ----
// thread c (0..7) covers cols {c*8..c*8+7} and {64+c*8..64+c*8+7}: its two
// b128 loads per matrix land at row+c*16 and row+128B+c*16, so each wave
// instruction covers 8 edges x one FULL 128B line (minimal line transactions).
__launch_bounds__(256)
__global__ void edge_mlp(const _Float16* __restrict__ ws,
                         const int* __restrict__ src_idx,
                         const int* __restrict__ dst_idx,
                         const float* __restrict__ W2,
                         const float* __restrict__ b2p,
                         float* __restrict__ out) {
    const int tid = threadIdx.x;
    const int c   = tid & 7;
    const int e   = blockIdx.x * 32 + (tid >> 3);

    const int s = src_idx[e];
    const int d = dst_idx[e];

    const _Float16* pr = ws + P_OFF + (long)s * H + c * 8;
    const _Float16* qr = ws + Q_OFF + (long)d * H + c * 8;

    half8 p0 = *(const half8*)(pr);
    half8 p1 = *(const half8*)(pr + 64);
    half8 q0 = *(const half8*)(qr);
    half8 q1 = *(const half8*)(qr + 64);

    // W2 quarter in f32 (broadcast across edges; L1-resident)
    const float* w2a = W2 + c * 8;
    float4 wa0 = *(const float4*)(w2a);
    float4 wa1 = *(const float4*)(w2a + 4);
    float4 wb0 = *(const float4*)(w2a + 64);
    float4 wb1 = *(const float4*)(w2a + 68);

    half8 h0 = p0 + q0;   // v_pk_add_f16
    half8 h1 = p1 + q1;

    float acc = 0.0f;
    const float* wa = (const float*)&wa0;   // wa0,wa1 contiguous? use per-vec
    (void)wa;
#pragma unroll
    for (int i = 0; i < 4; ++i) {
        float v = fmaxf((float)h0[i], 0.0f);
        acc = fmaf(v, ((const float*)&wa0)[i], acc);
    }
#pragma unroll
    for (int i = 0; i < 4; ++i) {
        float v = fmaxf((float)h0[i + 4], 0.0f);
        acc = fmaf(v, ((const float*)&wa1)[i], acc);
    }
#pragma unroll
    for (int i = 0; i < 4; ++i) {
        float v = fmaxf((float)h1[i], 0.0f);
        acc = fmaf(v, ((const float*)&wb0)[i], acc);
    }
#pragma unroll
    for (int i = 0; i < 4; ++i) {
        float v = fmaxf((float)h1[i + 4], 0.0f);
        acc = fmaf(v, ((const float*)&wb1)[i], acc);
    }

    // reduce over the 8-lane edge group
    acc += __shfl_xor(acc, 1);
    acc += __shfl_xor(acc, 2);
    acc += __shfl_xor(acc, 4);

    if (c == 0)
        out[e] = 1.0f / (1.0f + expf(-(acc + b2p[0])));
}

extern "C" void kernel_launch(void* const* d_in, const int* in_sizes, int n_in,
                              void* d_out, int out_size, void* d_ws, size_t ws_size,
                              hipStream_t stream) {
    const float* xin  = (const float*)d_in[0];
    const float* xcmp = (const float*)d_in[1];
    const int*   eidx = (const int*)d_in[2];    // [2, E]: first E = src, next E = dst
    const float* W1   = (const float*)d_in[3];
    const float* b1   = (const float*)d_in[4];
    const float* W2   = (const float*)d_in[5];
    const float* b2   = (const float*)d_in[6];
    float* out = (float*)d_out;
    _Float16* ws = (_Float16*)d_ws;             // 7.68 MB used

    hipLaunchKernelGGL(pq_gemm, dim3(PB + QB), dim3(256), 0, stream,
                       xin, xcmp, W1, b1, ws);
    hipLaunchKernelGGL(edge_mlp, dim3(NE / 32), dim3(256), 0, stream,
                       ws, eidx, eidx + NE, W2, b2, out);
}